// Round 8
// baseline (66.662 us; speedup 1.0000x reference)
//
#include <hip/hip_runtime.h>

#define NCH 256
#define ROIS_ELEMS 50176000              // 800*7*7*1280

typedef float vf4 __attribute__((ext_vector_type(4)));

// One wave per output cell (box, py, px), all 5 levels; boxes processed in
// y-sorted order per image (ranked in LDS per block) so the per-XCD fm read
// stream sweeps top-to-bottom. Output written at ORIGINAL box index.
// 800*49 = 39200 cells; 4 waves/block -> 9800 blocks = 8 * 1225 (XCD=image).
__global__ __launch_bounds__(256) void roi_cell_kernel(
    const float* __restrict__ boxes,   // [800,4] image-space (y1,x1,y2,x2)
    const float* __restrict__ fm0,
    const float* __restrict__ fm1,
    const float* __restrict__ fm2,
    const float* __restrict__ fm3,
    const float* __restrict__ fm4,
    float* __restrict__ out,           // [800,7,7,1280]
    float* __restrict__ out_ids)       // [800] written as float
{
    const int wave = threadIdx.x >> 6;
    const int lane = threadIdx.x & 63;

    // XCD-chunked bijective swizzle: 9800 = 8 * 1225 exactly (XCD = image).
    const int bswz = (blockIdx.x & 7) * 1225 + (blockIdx.x >> 3);
    const int simg = bswz / 1225;              // image this block serves

    // Rank this image's 100 boxes by y-center (deterministic, bijective).
    __shared__ float sy[100];
    __shared__ int   inv[100];                 // sorted rank -> box-within-image
    const int t = threadIdx.x;
    if (t < 100) {
        const float* bb = boxes + (simg * 100 + t) * 4;
        sy[t] = bb[0] + bb[2];                 // y1 + y2 (2*center)
    }
    __syncthreads();
    if (t < 100) {
        const float my = sy[t];
        int r = 0;
        for (int j = 0; j < 100; ++j) {
            const float o = sy[j];
            r += (o < my || (o == my && j < t)) ? 1 : 0;
        }
        inv[r] = t;
    }
    __syncthreads();

    const int cellS  = bswz * 4 + wave;        // sorted-cell id [0,39200)
    const int within = cellS - simg * 4900;    // [0,4900)
    const int sIdx   = within / 49;            // sorted box rank in image
    const int rem    = within - sIdx * 49;
    const int py     = rem / 7;
    const int px     = rem - py * 7;
    const int n      = simg * 100 + inv[sIdx]; // ORIGINAL box index
    const int img    = simg;

    const float* fms[5] = { fm0, fm1, fm2, fm3, fm4 };

    const float y1 = boxes[n * 4 + 0];
    const float x1 = boxes[n * 4 + 1];
    const float y2 = boxes[n * 4 + 2];
    const float x2 = boxes[n * 4 + 3];

    const float fy = __fdiv_rn((float)py, 6.0f);
    const float fx = __fdiv_rn((float)px, 6.0f);

    // Phase 1: per-level coords (reference-exact numerics) + scalar offsets.
    float wy_[5], owy_[5], wx_[5], owx_[5];
    bool  vv_[5];
    int o00[5], o01[5], o10[5], o11[5];
    #pragma unroll
    for (int l = 0; l < 5; ++l) {
        const int   H    = 128 >> l;
        const float Hm1  = (float)(H - 1);
        const float scale = (float)((8 << l) * (H - 1));   // exact in f32

        const float y1n = __fdiv_rn(y1, scale);
        const float y2n = __fdiv_rn(y2, scale);
        const float x1n = __fdiv_rn(x1, scale);
        const float x2n = __fdiv_rn(x2, scale);

        const float ys = __fmul_rn(__fadd_rn(y1n, __fmul_rn(__fsub_rn(y2n, y1n), fy)), Hm1);
        const float xs = __fmul_rn(__fadd_rn(x1n, __fmul_rn(__fsub_rn(x2n, x1n), fx)), Hm1);
        vv_[l] = (ys >= 0.0f) && (ys <= Hm1) && (xs >= 0.0f) && (xs <= Hm1);

        const float y0f = floorf(ys);
        const float x0f = floorf(xs);
        wy_[l] = ys - y0f;  owy_[l] = 1.0f - wy_[l];
        wx_[l] = xs - x0f;  owx_[l] = 1.0f - wx_[l];

        const int y0  = (int)fminf(fmaxf(y0f,        0.0f), Hm1);
        const int y1i = (int)fminf(fmaxf(y0f + 1.0f, 0.0f), Hm1);
        const int x0  = (int)fminf(fmaxf(x0f,        0.0f), Hm1);
        const int x1i = (int)fminf(fmaxf(x0f + 1.0f, 0.0f), Hm1);

        const int rowT = (img * H + y0 ) * H;
        const int rowB = (img * H + y1i) * H;
        o00[l] = __builtin_amdgcn_readfirstlane((rowT + x0 ) * NCH);
        o01[l] = __builtin_amdgcn_readfirstlane((rowT + x1i) * NCH);
        o10[l] = __builtin_amdgcn_readfirstlane((rowB + x0 ) * NCH);
        o11[l] = __builtin_amdgcn_readfirstlane((rowB + x1i) * NCH);
    }

    // Phase 2: issue all 20 corner loads (1 KB each, coalesced) -> max MLP.
    vf4 v00[5], v01[5], v10[5], v11[5];
    #pragma unroll
    for (int l = 0; l < 5; ++l) {
        const float* fm = fms[l];
        v00[l] = ((const vf4*)(fm + o00[l]))[lane];
        v01[l] = ((const vf4*)(fm + o01[l]))[lane];
        v10[l] = ((const vf4*)(fm + o10[l]))[lane];
        v11[l] = ((const vf4*)(fm + o11[l]))[lane];
    }

    // Phase 3: blend + one contiguous 5120 B NT write burst (5 x 1 KB).
    float* obase = out + (n * 49 + rem) * 1280;
    #pragma unroll
    for (int l = 0; l < 5; ++l) {
        vf4 r = (v00[l] * owx_[l] + v01[l] * wx_[l]) * owy_[l]
              + (v10[l] * owx_[l] + v11[l] * wx_[l]) * wy_[l];
        if (!vv_[l]) { r = (vf4)0.0f; }
        __builtin_nontemporal_store(r, ((vf4*)(obase + l * NCH)) + lane);
    }

    if (rem == 0 && lane == 0) {
        out_ids[n] = (float)img;
    }
}

extern "C" void kernel_launch(void* const* d_in, const int* in_sizes, int n_in,
                              void* d_out, int out_size, void* d_ws, size_t ws_size,
                              hipStream_t stream) {
    const float* boxes = (const float*)d_in[0];
    const float* fm0   = (const float*)d_in[1];
    const float* fm1   = (const float*)d_in[2];
    const float* fm2   = (const float*)d_in[3];
    const float* fm3   = (const float*)d_in[4];
    const float* fm4   = (const float*)d_in[5];

    float* out     = (float*)d_out;
    float* out_ids = out + ROIS_ELEMS;

    roi_cell_kernel<<<9800, 256, 0, stream>>>(boxes, fm0, fm1, fm2, fm3, fm4, out, out_ids);
}